// Round 1
// baseline (431.358 us; speedup 1.0000x reference)
//
#include <hip/hip_runtime.h>
#include <hip/hip_bf16.h>

// Problem: MatcherSimple — batched rectangular linear_sum_assignment (JV
// shortest augmenting path), B=8, P=4096 proposals (cols), G=96 GT (rows).
// cost[b][p][g] = center_dist - 2*gious ; LSA runs on transpose [G x P].
// Outputs (concat float): per_prop_gt_inds [B,P], proposal_matched_mask [B,P].

#define P_N 4096
#define G_M 96
#define BLK 1024
#define WAVES (BLK / 64)

__device__ __forceinline__ void lexmin(float& bv, int& bi, float ov, int oi) {
    if (ov < bv || (ov == bv && oi < bi)) { bv = ov; bi = oi; }
}

// ---- cost transpose: out[b][g][p] = cd[b][p][g] - 2*gi[b][p][g] -----------
__global__ __launch_bounds__(256) void cost_transpose(
    const float* __restrict__ cd, const float* __restrict__ gi,
    float* __restrict__ out)
{
    __shared__ float tile[64][G_M + 1];
    int b  = blockIdx.x >> 6;          // P/64 = 64 tiles per batch
    int pb = (blockIdx.x & 63) * 64;
    size_t base = ((size_t)b * P_N + pb) * G_M;
    for (int t = threadIdx.x; t < 64 * G_M; t += 256) {
        int p = t / G_M, g = t - p * G_M;
        tile[p][g] = cd[base + t] - 2.0f * gi[base + t];
    }
    __syncthreads();
    for (int t = threadIdx.x; t < 64 * G_M; t += 256) {
        int g = t >> 6, p = t & 63;
        out[((size_t)b * G_M + g) * P_N + pb + p] = tile[p][g];
    }
}

// ---- LSA: one block per batch ---------------------------------------------
__global__ __launch_bounds__(BLK) void lsa_kernel(
    const float* __restrict__ costT,           // [B,G,P] or nullptr
    const float* __restrict__ cd, const float* __restrict__ gi,
    const int* __restrict__ nactual,
    float* __restrict__ out, int B)
{
    const int b = blockIdx.x, tid = threadIdx.x;
    const float BIGF = 1e9f;

    __shared__ float v[P_N];
    __shared__ float shortest[P_N];
    __shared__ short path[P_N];
    __shared__ short row4col[P_N];
    __shared__ unsigned char SC[P_N];
    __shared__ float u[G_M];
    __shared__ short col4row[G_M];
    __shared__ unsigned char SR[G_M];
    __shared__ float s_minval;
    __shared__ int s_j, s_cur, s_done;
    __shared__ float rv[WAVES];
    __shared__ int ri[WAVES];

    for (int j = tid; j < P_N; j += BLK) { v[j] = 0.0f; row4col[j] = -1; }
    if (tid < G_M) { u[tid] = 0.0f; col4row[tid] = -1; }
    const int nrows = nactual[b];
    __syncthreads();

    for (int i = 0; i < nrows; ++i) {
        for (int j = tid; j < P_N; j += BLK) {
            shortest[j] = BIGF; path[j] = -1; SC[j] = 0;
        }
        if (tid < G_M) SR[tid] = 0;
        if (tid == 0) s_done = 0;
        __syncthreads();

        float minval = 0.0f;
        int cur = i;
        int sink = -1;

        while (true) {
            if (tid == 0) SR[cur] = 1;
            const float ucur = u[cur];
            const float* crow =
                costT ? (costT + ((size_t)b * G_M + cur) * P_N) : nullptr;

            // reduced-cost relaxation over all unscanned columns
            #pragma unroll
            for (int k = 0; k < P_N / BLK; ++k) {
                int j = tid + k * BLK;
                if (!SC[j]) {
                    float c;
                    if (crow) c = crow[j];
                    else {
                        size_t idx = ((size_t)b * P_N + j) * G_M + cur;
                        c = cd[idx] - 2.0f * gi[idx];
                    }
                    float red = ((minval + c) - ucur) - v[j];
                    if (red < shortest[j]) { shortest[j] = red; path[j] = (short)cur; }
                }
            }
            __syncthreads();

            // argmin over cand = SC ? BIG : shortest (first-occurrence tiebreak)
            float bv = 3.0e38f; int bi = P_N;
            #pragma unroll
            for (int k = 0; k < P_N / BLK; ++k) {
                int j = tid + k * BLK;
                float cval = SC[j] ? BIGF : shortest[j];
                lexmin(bv, bi, cval, j);
            }
            #pragma unroll
            for (int off = 32; off > 0; off >>= 1) {
                float ov = __shfl_xor(bv, off, 64);
                int   oi = __shfl_xor(bi, off, 64);
                lexmin(bv, bi, ov, oi);
            }
            if ((tid & 63) == 0) { rv[tid >> 6] = bv; ri[tid >> 6] = bi; }
            __syncthreads();
            if (tid == 0) {
                float mv = rv[0]; int mi = ri[0];
                for (int w = 1; w < WAVES; ++w) lexmin(mv, mi, rv[w], ri[w]);
                s_minval = mv; s_j = mi; SC[mi] = 1;
                int r = row4col[mi];
                if (r < 0) s_done = 1; else s_cur = r;
            }
            __syncthreads();
            minval = s_minval;
            if (s_done) { sink = s_j; break; }
            cur = s_cur;
        }

        // dual updates (scipy rectangular_lsap order, pre-augmentation col4row)
        if (tid < G_M) {
            if (tid == i) {
                u[tid] = u[tid] + minval;
            } else if (SR[tid]) {
                int c = col4row[tid]; if (c < 0) c = 0;  // clip
                u[tid] = (u[tid] + minval) - shortest[c];
            }
        }
        #pragma unroll
        for (int k = 0; k < P_N / BLK; ++k) {
            int j = tid + k * BLK;
            if (SC[j]) v[j] = v[j] - (minval - shortest[j]);
        }
        __syncthreads();

        // augment alternating path (sequential, tiny)
        if (tid == 0) {
            int j = sink;
            while (true) {
                int r = path[j];
                row4col[j] = (short)r;
                int jn = col4row[r];
                col4row[r] = (short)j;
                if (r == i) break;
                j = jn;
            }
        }
        __syncthreads();
    }

    // outputs: inds then mask, each [B, P], as float
    float* out_inds = out + (size_t)b * P_N;
    float* out_mask = out + (size_t)B * P_N + (size_t)b * P_N;
    for (int j = tid; j < P_N; j += BLK) {
        int r = row4col[j];
        out_inds[j] = (r >= 0) ? (float)r : 0.0f;
        out_mask[j] = (r >= 0) ? 1.0f : 0.0f;
    }
}

extern "C" void kernel_launch(void* const* d_in, const int* in_sizes, int n_in,
                              void* d_out, int out_size, void* d_ws, size_t ws_size,
                              hipStream_t stream) {
    const float* cd = (const float*)d_in[0];
    const float* gi = (const float*)d_in[1];
    const int*   na = (const int*)d_in[2];
    float* out = (float*)d_out;
    const int B = in_sizes[2];   // 8

    const size_t need = (size_t)B * G_M * P_N * sizeof(float);
    float* costT = nullptr;
    if (ws_size >= need) {
        costT = (float*)d_ws;
        cost_transpose<<<dim3(B * (P_N / 64)), 256, 0, stream>>>(cd, gi, costT);
    }
    lsa_kernel<<<dim3(B), BLK, 0, stream>>>(costT, cd, gi, na, out, B);
}

// Round 2
// 353.103 us; speedup vs baseline: 1.2216x; 1.2216x over previous
//
#include <hip/hip_runtime.h>
#include <hip/hip_bf16.h>

// MatcherSimple — batched rectangular LSA (JV shortest augmenting path).
// B=8, P=4096 proposals (cols), G=96 GT (rows). cost = center_dist - 2*gious.
// Round 2: column reduction — optimum only uses each row's 96 smallest cols
// (unique optimum w.p.1 for continuous costs), so run exact JV on top-96
// candidate lists with a frontier-based Dijkstra in a single 64-lane wave.

#define P_N 4096
#define G_M 96
#define KCAP 128          // candidate slots per row (>=96; slack for ties)
#define BIGF 1e9f

__device__ __forceinline__ void lexmin(float& bv, int& bi, float ov, int oi) {
    if (ov < bv || (ov == bv && oi < bi)) { bv = ov; bi = oi; }
}

// ---- cost + transpose: costT[b][g][p] = cd[b][p][g] - 2*gi[b][p][g] -------
__global__ __launch_bounds__(256) void cost_transpose(
    const float* __restrict__ cd, const float* __restrict__ gi,
    float* __restrict__ out)
{
    __shared__ float tile[64][G_M + 1];
    int b  = blockIdx.x >> 6;          // P/64 = 64 tiles per batch
    int pb = (blockIdx.x & 63) * 64;
    size_t base = ((size_t)b * P_N + pb) * G_M;
    for (int t = threadIdx.x; t < 64 * G_M; t += 256) {
        int p = t / G_M, g = t - p * G_M;
        tile[p][g] = cd[base + t] - 2.0f * gi[base + t];
    }
    __syncthreads();
    for (int t = threadIdx.x; t < 64 * G_M; t += 256) {
        int g = t >> 6, p = t & 63;
        out[((size_t)b * G_M + g) * P_N + pb + p] = tile[p][g];
    }
}

// ---- top-96 per row via MSD radix select on ordered float keys ------------
__global__ __launch_bounds__(256) void topk_kernel(
    const float* __restrict__ costT,
    unsigned short* __restrict__ cand_idx,
    float* __restrict__ cand_cost,
    int* __restrict__ cand_cnt)
{
    const int row = blockIdx.x;            // b*G_M + g
    const int tid = threadIdx.x;
    const float* crow = costT + (size_t)row * P_N;

    __shared__ unsigned int keys[P_N];     // 16 KB
    __shared__ unsigned int hist[256];
    __shared__ unsigned int cum[256];
    __shared__ unsigned int s_digit, s_K;
    __shared__ int s_cnt;

    for (int t = tid; t < P_N; t += 256) {
        unsigned int u = __float_as_uint(crow[t]);
        keys[t] = u ^ ((unsigned int)((int)u >> 31) | 0x80000000u);  // order-preserving
    }
    if (tid == 0) s_cnt = 0;
    __syncthreads();

    unsigned int prefix = 0, prefmask = 0;
    int K = G_M;                            // rank-96 (1-indexed)
    for (int pass = 0; pass < 4; ++pass) {
        const int shift = 24 - 8 * pass;
        hist[tid] = 0;
        __syncthreads();
        for (int t = tid; t < P_N; t += 256) {
            unsigned int k = keys[t];
            if ((k & prefmask) == prefix)
                atomicAdd(&hist[(k >> shift) & 255u], 1u);
        }
        __syncthreads();
        if (tid < 64) {                     // wave-0 inclusive scan, 4 bins/lane
            unsigned int h0 = hist[4*tid], h1 = hist[4*tid+1];
            unsigned int h2 = hist[4*tid+2], h3 = hist[4*tid+3];
            unsigned int lsum = h0 + h1 + h2 + h3;
            unsigned int sc = lsum;
            for (int off = 1; off < 64; off <<= 1) {
                unsigned int o = __shfl_up(sc, off, 64);
                if (tid >= off) sc += o;
            }
            unsigned int excl = sc - lsum;
            cum[4*tid]   = excl + h0;
            cum[4*tid+1] = excl + h0 + h1;
            cum[4*tid+2] = excl + h0 + h1 + h2;
            cum[4*tid+3] = excl + lsum;
        }
        __syncthreads();
        {
            unsigned int hi = cum[tid];
            unsigned int lo = tid ? cum[tid - 1] : 0u;
            if (lo < (unsigned)K && (unsigned)K <= hi) {
                s_digit = (unsigned)tid; s_K = (unsigned)K - lo;
            }
        }
        __syncthreads();
        prefix |= (s_digit << shift);
        prefmask |= (255u << shift);
        K = (int)s_K;
        __syncthreads();
    }
    const unsigned int T = prefix;          // exact 96th-smallest key

    for (int t = tid; t < P_N; t += 256) {
        unsigned int k = keys[t];
        if (k <= T) {
            int slot = atomicAdd(&s_cnt, 1);
            if (slot < KCAP) {
                unsigned int u = (k & 0x80000000u) ? (k ^ 0x80000000u) : ~k;
                cand_idx[(size_t)row * KCAP + slot] = (unsigned short)t;
                cand_cost[(size_t)row * KCAP + slot] = __uint_as_float(u);
            }
        }
    }
    __syncthreads();
    if (tid == 0) cand_cnt[row] = s_cnt < KCAP ? s_cnt : KCAP;
}

// ---- reduced JV LSA: one 64-lane wave per batch ---------------------------
__global__ __launch_bounds__(64) void lsa_reduced(
    const unsigned short* __restrict__ cand_idx,
    const float* __restrict__ cand_cost,
    const int* __restrict__ cand_cnt,
    const int* __restrict__ nactual,
    float* __restrict__ out, int B)
{
    const int b = blockIdx.x;
    const int tid = threadIdx.x;

    __shared__ float shortest[P_N];          // 16 KB (indexed by global col)
    __shared__ float v[P_N];                 // 16 KB
    __shared__ short pathr[P_N];             // 8 KB
    __shared__ short row4col[P_N];           // 8 KB
    __shared__ unsigned char SC[P_N];        // 4 KB
    __shared__ unsigned short frontier[P_N]; // 8 KB (each col enters once/round)
    __shared__ float u[G_M];
    __shared__ short col4row[G_M];
    __shared__ unsigned char SR[G_M];
    __shared__ int s_fcnt;

    for (int j = tid; j < P_N; j += 64) {
        shortest[j] = BIGF; v[j] = 0.0f; SC[j] = 0; row4col[j] = -1;
    }
    for (int r = tid; r < G_M; r += 64) { u[r] = 0.0f; col4row[r] = -1; SR[r] = 0; }
    if (tid == 0) s_fcnt = 0;
    const int nrows = nactual[b];
    __syncthreads();

    for (int i = 0; i < nrows; ++i) {
        float minval = 0.0f;
        int cur = i, sink = -1;

        for (int guard = 0; guard < P_N + 8; ++guard) {
            if (tid == 0) SR[cur] = 1;
            const int rbase = (b * G_M + cur) * KCAP;
            const int cnt = cand_cnt[b * G_M + cur];
            const float ucur = u[cur];
            for (int t = tid; t < cnt; t += 64) {
                const int j = cand_idx[rbase + t];
                if (!SC[j]) {
                    float red = minval + cand_cost[rbase + t] - ucur - v[j];
                    if (red < shortest[j]) {
                        if (shortest[j] >= BIGF) {       // first touch -> frontier
                            int s = atomicAdd(&s_fcnt, 1);
                            frontier[s] = (unsigned short)j;
                        }
                        shortest[j] = red; pathr[j] = (short)cur;
                    }
                }
            }
            __syncthreads();                              // single-wave: cheap
            const int F = s_fcnt;
            float bv = 3.0e38f; int bi = P_N;
            for (int t = tid; t < F; t += 64) {
                const int j = frontier[t];
                lexmin(bv, bi, SC[j] ? BIGF : shortest[j], j);
            }
            #pragma unroll
            for (int off = 32; off > 0; off >>= 1) {
                float ov = __shfl_xor(bv, off, 64);
                int   oi = __shfl_xor(bi, off, 64);
                lexmin(bv, bi, ov, oi);
            }
            minval = bv;
            if (bi >= P_N) { sink = -2; break; }          // impossible; no-hang guard
            if (tid == 0) SC[bi] = 1;
            const int r = row4col[bi];
            if (r < 0) { sink = bi; break; }              // free column found
            cur = r;
            __syncthreads();                              // SC visible to next relax
        }
        __syncthreads();

        // dual u updates (pre-augmentation col4row), scipy order
        if (sink >= 0) {
            for (int r = tid; r < G_M; r += 64) {
                if (r == i) u[r] += minval;
                else if (SR[r]) {
                    int c = col4row[r]; if (c < 0) c = 0;
                    u[r] += minval - shortest[c];
                }
            }
        }
        __syncthreads();

        // augment: flip alternating path (lane 0)
        if (sink >= 0 && tid == 0) {
            int j = sink;
            for (int g2 = 0; g2 < G_M + 2; ++g2) {
                int r = pathr[j];
                row4col[j] = (short)r;
                int jn = col4row[r];
                col4row[r] = (short)j;
                if (r == i) break;
                j = jn;
            }
        }
        __syncthreads();

        // frontier sweep: v update for scanned cols, reset state for next round
        const int F = s_fcnt;
        for (int t = tid; t < F; t += 64) {
            const int j = frontier[t];
            if (SC[j]) v[j] -= (minval - shortest[j]);
            SC[j] = 0;
            shortest[j] = BIGF;
        }
        for (int r = tid; r < G_M; r += 64) SR[r] = 0;
        if (tid == 0) s_fcnt = 0;
        __syncthreads();
    }

    // outputs: inds then mask, each [B, P], float
    float* out_inds = out + (size_t)b * P_N;
    float* out_mask = out + (size_t)B * P_N + (size_t)b * P_N;
    for (int j = tid; j < P_N; j += 64) {
        int r = row4col[j];
        out_inds[j] = (r >= 0) ? (float)r : 0.0f;
        out_mask[j] = (r >= 0) ? 1.0f : 0.0f;
    }
}

// ---- fallback: round-1 full-sweep LSA (used only if workspace too small) --
#define BLK 1024
#define WAVES (BLK / 64)
__global__ __launch_bounds__(BLK) void lsa_full(
    const float* __restrict__ cd, const float* __restrict__ gi,
    const int* __restrict__ nactual,
    float* __restrict__ out, int B)
{
    const int b = blockIdx.x, tid = threadIdx.x;
    __shared__ float v[P_N];
    __shared__ float shortest[P_N];
    __shared__ short path[P_N];
    __shared__ short row4col[P_N];
    __shared__ unsigned char SC[P_N];
    __shared__ float u[G_M];
    __shared__ short col4row[G_M];
    __shared__ unsigned char SR[G_M];
    __shared__ float s_minval;
    __shared__ int s_j, s_cur, s_done;
    __shared__ float rv[WAVES];
    __shared__ int ri[WAVES];

    for (int j = tid; j < P_N; j += BLK) { v[j] = 0.0f; row4col[j] = -1; }
    if (tid < G_M) { u[tid] = 0.0f; col4row[tid] = -1; }
    const int nrows = nactual[b];
    __syncthreads();

    for (int i = 0; i < nrows; ++i) {
        for (int j = tid; j < P_N; j += BLK) { shortest[j] = BIGF; path[j] = -1; SC[j] = 0; }
        if (tid < G_M) SR[tid] = 0;
        if (tid == 0) s_done = 0;
        __syncthreads();
        float minval = 0.0f; int cur = i, sink = -1;
        while (true) {
            if (tid == 0) SR[cur] = 1;
            const float ucur = u[cur];
            #pragma unroll
            for (int k = 0; k < P_N / BLK; ++k) {
                int j = tid + k * BLK;
                if (!SC[j]) {
                    size_t idx = ((size_t)b * P_N + j) * G_M + cur;
                    float c = cd[idx] - 2.0f * gi[idx];
                    float red = ((minval + c) - ucur) - v[j];
                    if (red < shortest[j]) { shortest[j] = red; path[j] = (short)cur; }
                }
            }
            __syncthreads();
            float bv = 3.0e38f; int bi = P_N;
            #pragma unroll
            for (int k = 0; k < P_N / BLK; ++k) {
                int j = tid + k * BLK;
                lexmin(bv, bi, SC[j] ? BIGF : shortest[j], j);
            }
            #pragma unroll
            for (int off = 32; off > 0; off >>= 1) {
                float ov = __shfl_xor(bv, off, 64);
                int oi = __shfl_xor(bi, off, 64);
                lexmin(bv, bi, ov, oi);
            }
            if ((tid & 63) == 0) { rv[tid >> 6] = bv; ri[tid >> 6] = bi; }
            __syncthreads();
            if (tid == 0) {
                float mv = rv[0]; int mi = ri[0];
                for (int w = 1; w < WAVES; ++w) lexmin(mv, mi, rv[w], ri[w]);
                s_minval = mv; s_j = mi; SC[mi] = 1;
                int r = row4col[mi];
                if (r < 0) s_done = 1; else s_cur = r;
            }
            __syncthreads();
            minval = s_minval;
            if (s_done) { sink = s_j; break; }
            cur = s_cur;
        }
        if (tid < G_M) {
            if (tid == i) u[tid] += minval;
            else if (SR[tid]) {
                int c = col4row[tid]; if (c < 0) c = 0;
                u[tid] = (u[tid] + minval) - shortest[c];
            }
        }
        #pragma unroll
        for (int k = 0; k < P_N / BLK; ++k) {
            int j = tid + k * BLK;
            if (SC[j]) v[j] -= (minval - shortest[j]);
        }
        __syncthreads();
        if (tid == 0) {
            int j = sink;
            while (true) {
                int r = path[j];
                row4col[j] = (short)r;
                int jn = col4row[r];
                col4row[r] = (short)j;
                if (r == i) break;
                j = jn;
            }
        }
        __syncthreads();
    }
    float* out_inds = out + (size_t)b * P_N;
    float* out_mask = out + (size_t)B * P_N + (size_t)b * P_N;
    for (int j = tid; j < P_N; j += BLK) {
        int r = row4col[j];
        out_inds[j] = (r >= 0) ? (float)r : 0.0f;
        out_mask[j] = (r >= 0) ? 1.0f : 0.0f;
    }
}

extern "C" void kernel_launch(void* const* d_in, const int* in_sizes, int n_in,
                              void* d_out, int out_size, void* d_ws, size_t ws_size,
                              hipStream_t stream) {
    const float* cd = (const float*)d_in[0];
    const float* gi = (const float*)d_in[1];
    const int*   na = (const int*)d_in[2];
    float* out = (float*)d_out;
    const int B = in_sizes[2];   // 8

    const size_t costT_b = (size_t)B * G_M * P_N * sizeof(float);
    const size_t ci_b    = (size_t)B * G_M * KCAP * sizeof(unsigned short);
    const size_t cc_b    = (size_t)B * G_M * KCAP * sizeof(float);
    const size_t cn_b    = (size_t)B * G_M * sizeof(int);
    auto al = [](size_t x) { return (x + 255) & ~(size_t)255; };
    const size_t o1 = al(costT_b);
    const size_t o2 = o1 + al(ci_b);
    const size_t o3 = o2 + al(cc_b);
    const size_t need = o3 + al(cn_b);

    if (ws_size >= need) {
        float* costT = (float*)d_ws;
        unsigned short* cidx = (unsigned short*)((char*)d_ws + o1);
        float* ccost = (float*)((char*)d_ws + o2);
        int* ccnt = (int*)((char*)d_ws + o3);
        cost_transpose<<<dim3(B * (P_N / 64)), 256, 0, stream>>>(cd, gi, costT);
        topk_kernel<<<dim3(B * G_M), 256, 0, stream>>>(costT, cidx, ccost, ccnt);
        lsa_reduced<<<dim3(B), 64, 0, stream>>>(cidx, ccost, ccnt, na, out, B);
    } else {
        lsa_full<<<dim3(B), BLK, 0, stream>>>(cd, gi, na, out, B);
    }
}

// Round 3
// 111.019 us; speedup vs baseline: 3.8854x; 3.1806x over previous
//
#include <hip/hip_runtime.h>
#include <hip/hip_bf16.h>

// MatcherSimple — batched rectangular LSA (JV shortest augmenting path).
// B=8, P=4096 cols (proposals), G=96 rows (GT). cost = center_dist - 2*gious.
// Round 3: JV row-reduction init. u[i]=min_j c[i,j], v=0, greedy-assign argmin
// cols (expected ~1 collision/batch) -> only leftover rows run Dijkstra.
// Exact optimum is unique w.p.1 for continuous costs => matches reference.

#define P_N 4096
#define G_M 96
#define BIGF 1e9f
#define NCHUNK (P_N / 256)   // 16: chunk = 256 cols = 64 lanes x float4

__device__ __forceinline__ void lexmin(float& bv, int& bi, float ov, int oi) {
    if (ov < bv || (ov == bv && oi < bi)) { bv = ov; bi = oi; }
}
__device__ __forceinline__ unsigned int ord32(float f) {
    unsigned int u = __float_as_uint(f);
    return u ^ ((unsigned int)((int)u >> 31) | 0x80000000u);
}
__device__ __forceinline__ float unord32(unsigned int k) {
    unsigned int u = (k & 0x80000000u) ? (k ^ 0x80000000u) : ~k;
    return __uint_as_float(u);
}

// ---- cost build + transpose + per-row argmin ------------------------------
// costT[b][g][p] = cd[b][p][g] - 2*gi[b][p][g]; rowmin[b*G+g] = min-packed
// (ord(cost)<<32 | p)  -> global u64 atomicMin across 64-col stripes.
__global__ __launch_bounds__(256) void cost_prep(
    const float* __restrict__ cd, const float* __restrict__ gi,
    float* __restrict__ costT, unsigned long long* __restrict__ rowmin)
{
    __shared__ float tile[64][G_M + 1];
    int b  = blockIdx.x >> 6;          // 64 stripes of 64 cols per batch
    int pb = (blockIdx.x & 63) * 64;
    size_t base = ((size_t)b * P_N + pb) * G_M;
    for (int t = threadIdx.x; t < 64 * G_M; t += 256) {
        int p = t / G_M, g = t - p * G_M;
        tile[p][g] = cd[base + t] - 2.0f * gi[base + t];
    }
    __syncthreads();
    for (int t = threadIdx.x; t < 64 * G_M; t += 256) {
        int g = t >> 6, p = t & 63;
        costT[((size_t)b * G_M + g) * P_N + pb + p] = tile[p][g];
    }
    if (threadIdx.x < G_M) {
        int g = threadIdx.x;
        float bv = tile[0][g]; int bp = pb;
        #pragma unroll 8
        for (int p = 1; p < 64; ++p) {
            float val = tile[p][g];
            if (val < bv) { bv = val; bp = pb + p; }
        }
        unsigned long long pk =
            ((unsigned long long)ord32(bv) << 32) | (unsigned int)bp;
        atomicMin(&rowmin[b * G_M + g], pk);
    }
}

// ---- JV solve: one 64-lane wave per batch ---------------------------------
__global__ __launch_bounds__(64) void lsa_solve(
    const float* __restrict__ costT,
    const unsigned long long* __restrict__ rowmin,
    const int* __restrict__ nactual,
    float* __restrict__ out, int B)
{
    const int b = blockIdx.x, tid = threadIdx.x;

    __shared__ float v[P_N];                 // 16 KB
    __shared__ float shortest[P_N];          // 16 KB
    __shared__ short row4col[P_N];           // 8 KB
    __shared__ unsigned char pathr[P_N];     // 4 KB (rows < 96 fit u8)
    __shared__ unsigned char SC[P_N];        // 4 KB
    __shared__ float u[G_M];
    __shared__ short col4row[G_M];
    __shared__ short argc[G_M];
    __shared__ short pend[G_M];
    __shared__ unsigned char SR[G_M];
    __shared__ int s_npend;

    const int nrows = nactual[b];

    #pragma unroll
    for (int k = 0; k < NCHUNK; ++k) {
        int c = k * 256 + tid * 4;
        *(float4*)&v[c] = make_float4(0.f, 0.f, 0.f, 0.f);
        *(float4*)&shortest[c] = make_float4(BIGF, BIGF, BIGF, BIGF);
        *(unsigned int*)&SC[c] = 0u;
        *(uint2*)&row4col[c] = make_uint2(0xFFFFFFFFu, 0xFFFFFFFFu); // -1 shorts
    }
    for (int r = tid; r < G_M; r += 64) {
        unsigned long long pk = rowmin[b * G_M + r];
        u[r] = unord32((unsigned int)(pk >> 32));
        argc[r] = (short)(unsigned int)(pk & 0xFFFFFFFFu);
        col4row[r] = -1; SR[r] = 0;
    }
    __syncthreads();

    // greedy row-reduction assignment (lane 0, tiny)
    if (tid == 0) {
        int np = 0;
        for (int i = 0; i < nrows; ++i) {
            int j = argc[i];
            if (row4col[j] < 0) { row4col[j] = (short)i; col4row[i] = (short)j; }
            else pend[np++] = (short)i;
        }
        s_npend = np;
    }
    __syncthreads();
    const int npend = s_npend;

    // augment leftover rows with full-width Dijkstra
    for (int pi = 0; pi < npend; ++pi) {
        const int i = pend[pi];
        float minval = 0.0f;
        int cur = i, sink = -1;

        for (int guard = 0; guard <= P_N; ++guard) {
            __syncthreads();
            if (tid == 0) SR[cur] = 1;
            const float ucur = u[cur];
            const float4* crow =
                (const float4*)(costT + ((size_t)b * G_M + cur) * P_N);

            #pragma unroll 4
            for (int k = 0; k < NCHUNK; ++k) {
                int c = k * 256 + tid * 4;
                float4 cc = crow[c >> 2];
                float4 vv = *(const float4*)&v[c];
                float4 sh = *(const float4*)&shortest[c];
                unsigned int scw = *(const unsigned int*)&SC[c];
                float r0 = minval + cc.x - ucur - vv.x;
                float r1 = minval + cc.y - ucur - vv.y;
                float r2 = minval + cc.z - ucur - vv.z;
                float r3 = minval + cc.w - ucur - vv.w;
                if (!(scw & 0x000000FFu) && r0 < sh.x) { sh.x = r0; pathr[c+0] = (unsigned char)cur; }
                if (!(scw & 0x0000FF00u) && r1 < sh.y) { sh.y = r1; pathr[c+1] = (unsigned char)cur; }
                if (!(scw & 0x00FF0000u) && r2 < sh.z) { sh.z = r2; pathr[c+2] = (unsigned char)cur; }
                if (!(scw & 0xFF000000u) && r3 < sh.w) { sh.w = r3; pathr[c+3] = (unsigned char)cur; }
                *(float4*)&shortest[c] = sh;
            }
            __syncthreads();

            float bv = 3.0e38f; int bi = P_N;
            #pragma unroll 4
            for (int k = 0; k < NCHUNK; ++k) {
                int c = k * 256 + tid * 4;
                float4 sh = *(const float4*)&shortest[c];
                unsigned int scw = *(const unsigned int*)&SC[c];
                lexmin(bv, bi, (scw & 0x000000FFu) ? BIGF : sh.x, c + 0);
                lexmin(bv, bi, (scw & 0x0000FF00u) ? BIGF : sh.y, c + 1);
                lexmin(bv, bi, (scw & 0x00FF0000u) ? BIGF : sh.z, c + 2);
                lexmin(bv, bi, (scw & 0xFF000000u) ? BIGF : sh.w, c + 3);
            }
            #pragma unroll
            for (int off = 32; off > 0; off >>= 1) {
                float ov = __shfl_xor(bv, off, 64);
                int   oi = __shfl_xor(bi, off, 64);
                lexmin(bv, bi, ov, oi);
            }
            minval = bv;
            if (bi >= P_N) { sink = -2; break; }   // no-hang guard
            if (tid == 0) SC[bi] = 1;
            __syncthreads();
            int r = row4col[bi];                    // broadcast LDS read
            if (r < 0) { sink = bi; break; }
            cur = r;
        }
        __syncthreads();

        if (sink >= 0) {
            // dual u updates (pre-augmentation col4row)
            for (int r = tid; r < G_M; r += 64) {
                if (r == i) u[r] += minval;
                else if (SR[r]) {
                    int c4 = col4row[r]; if (c4 < 0) c4 = 0;
                    u[r] += minval - shortest[c4];
                }
            }
            __syncthreads();
            // v update for scanned cols; reset shortest/SC for next round
            #pragma unroll 4
            for (int k = 0; k < NCHUNK; ++k) {
                int c = k * 256 + tid * 4;
                unsigned int scw = *(const unsigned int*)&SC[c];
                if (scw) {
                    float4 sh = *(const float4*)&shortest[c];
                    float4 vv = *(float4*)&v[c];
                    if (scw & 0x000000FFu) vv.x -= minval - sh.x;
                    if (scw & 0x0000FF00u) vv.y -= minval - sh.y;
                    if (scw & 0x00FF0000u) vv.z -= minval - sh.z;
                    if (scw & 0xFF000000u) vv.w -= minval - sh.w;
                    *(float4*)&v[c] = vv;
                    *(unsigned int*)&SC[c] = 0u;
                }
                *(float4*)&shortest[c] = make_float4(BIGF, BIGF, BIGF, BIGF);
            }
            for (int r = tid; r < G_M; r += 64) SR[r] = 0;
            // augment: flip alternating path (lane 0)
            if (tid == 0) {
                int j = sink;
                for (int g2 = 0; g2 < G_M + 2; ++g2) {
                    int r = pathr[j];
                    row4col[j] = (short)r;
                    int jn = col4row[r];
                    col4row[r] = (short)j;
                    if (r == i) break;
                    j = jn;
                }
            }
            __syncthreads();
        }
    }

    float* out_inds = out + (size_t)b * P_N;
    float* out_mask = out + (size_t)B * P_N + (size_t)b * P_N;
    for (int j = tid; j < P_N; j += 64) {
        int r = row4col[j];
        out_inds[j] = (r >= 0) ? (float)r : 0.0f;
        out_mask[j] = (r >= 0) ? 1.0f : 0.0f;
    }
}

// ---- fallback: round-1 full-sweep LSA (only if workspace too small) -------
#define BLK 1024
#define WAVES (BLK / 64)
__global__ __launch_bounds__(BLK) void lsa_full(
    const float* __restrict__ cd, const float* __restrict__ gi,
    const int* __restrict__ nactual,
    float* __restrict__ out, int B)
{
    const int b = blockIdx.x, tid = threadIdx.x;
    __shared__ float v[P_N];
    __shared__ float shortest[P_N];
    __shared__ short path[P_N];
    __shared__ short row4col[P_N];
    __shared__ unsigned char SC[P_N];
    __shared__ float u[G_M];
    __shared__ short col4row[G_M];
    __shared__ unsigned char SR[G_M];
    __shared__ float s_minval;
    __shared__ int s_j, s_cur, s_done;
    __shared__ float rv[WAVES];
    __shared__ int ri[WAVES];

    for (int j = tid; j < P_N; j += BLK) { v[j] = 0.0f; row4col[j] = -1; }
    if (tid < G_M) { u[tid] = 0.0f; col4row[tid] = -1; }
    const int nrows = nactual[b];
    __syncthreads();

    for (int i = 0; i < nrows; ++i) {
        for (int j = tid; j < P_N; j += BLK) { shortest[j] = BIGF; path[j] = -1; SC[j] = 0; }
        if (tid < G_M) SR[tid] = 0;
        if (tid == 0) s_done = 0;
        __syncthreads();
        float minval = 0.0f; int cur = i, sink = -1;
        while (true) {
            if (tid == 0) SR[cur] = 1;
            const float ucur = u[cur];
            #pragma unroll
            for (int k = 0; k < P_N / BLK; ++k) {
                int j = tid + k * BLK;
                if (!SC[j]) {
                    size_t idx = ((size_t)b * P_N + j) * G_M + cur;
                    float c = cd[idx] - 2.0f * gi[idx];
                    float red = ((minval + c) - ucur) - v[j];
                    if (red < shortest[j]) { shortest[j] = red; path[j] = (short)cur; }
                }
            }
            __syncthreads();
            float bv = 3.0e38f; int bi = P_N;
            #pragma unroll
            for (int k = 0; k < P_N / BLK; ++k) {
                int j = tid + k * BLK;
                lexmin(bv, bi, SC[j] ? BIGF : shortest[j], j);
            }
            #pragma unroll
            for (int off = 32; off > 0; off >>= 1) {
                float ov = __shfl_xor(bv, off, 64);
                int oi = __shfl_xor(bi, off, 64);
                lexmin(bv, bi, ov, oi);
            }
            if ((tid & 63) == 0) { rv[tid >> 6] = bv; ri[tid >> 6] = bi; }
            __syncthreads();
            if (tid == 0) {
                float mv = rv[0]; int mi = ri[0];
                for (int w = 1; w < WAVES; ++w) lexmin(mv, mi, rv[w], ri[w]);
                s_minval = mv; s_j = mi; SC[mi] = 1;
                int r = row4col[mi];
                if (r < 0) s_done = 1; else s_cur = r;
            }
            __syncthreads();
            minval = s_minval;
            if (s_done) { sink = s_j; break; }
            cur = s_cur;
        }
        if (tid < G_M) {
            if (tid == i) u[tid] += minval;
            else if (SR[tid]) {
                int c = col4row[tid]; if (c < 0) c = 0;
                u[tid] = (u[tid] + minval) - shortest[c];
            }
        }
        #pragma unroll
        for (int k = 0; k < P_N / BLK; ++k) {
            int j = tid + k * BLK;
            if (SC[j]) v[j] -= (minval - shortest[j]);
        }
        __syncthreads();
        if (tid == 0) {
            int j = sink;
            while (true) {
                int r = path[j];
                row4col[j] = (short)r;
                int jn = col4row[r];
                col4row[r] = (short)j;
                if (r == i) break;
                j = jn;
            }
        }
        __syncthreads();
    }
    float* out_inds = out + (size_t)b * P_N;
    float* out_mask = out + (size_t)B * P_N + (size_t)b * P_N;
    for (int j = tid; j < P_N; j += BLK) {
        int r = row4col[j];
        out_inds[j] = (r >= 0) ? (float)r : 0.0f;
        out_mask[j] = (r >= 0) ? 1.0f : 0.0f;
    }
}

extern "C" void kernel_launch(void* const* d_in, const int* in_sizes, int n_in,
                              void* d_out, int out_size, void* d_ws, size_t ws_size,
                              hipStream_t stream) {
    const float* cd = (const float*)d_in[0];
    const float* gi = (const float*)d_in[1];
    const int*   na = (const int*)d_in[2];
    float* out = (float*)d_out;
    const int B = in_sizes[2];   // 8

    const size_t costT_b = (size_t)B * G_M * P_N * sizeof(float);
    const size_t rm_b    = (size_t)B * G_M * sizeof(unsigned long long);
    auto al = [](size_t x) { return (x + 255) & ~(size_t)255; };
    const size_t o1 = al(costT_b);
    const size_t need = o1 + al(rm_b);

    if (ws_size >= need) {
        float* costT = (float*)d_ws;
        unsigned long long* rowmin = (unsigned long long*)((char*)d_ws + o1);
        hipMemsetAsync(rowmin, 0xFF, rm_b, stream);   // u64 max
        cost_prep<<<dim3(B * (P_N / 64)), 256, 0, stream>>>(cd, gi, costT, rowmin);
        lsa_solve<<<dim3(B), 64, 0, stream>>>(costT, rowmin, na, out, B);
    } else {
        lsa_full<<<dim3(B), BLK, 0, stream>>>(cd, gi, na, out, B);
    }
}